// Round 5
// baseline (163.157 us; speedup 1.0000x reference)
//
#include <hip/hip_runtime.h>
#include <stdint.h>

// Problem constants (fixed by the reference)
#define B_IMG        64
#define M_GT         100
#define N_PROP       4000
#define K_TOT        4100          // N + M (proposal_append_gt)
#define NUM_CLASSES_ 80
#define BATCH_PER    512
#define NUM_FG_TGT   128
#define OUT_STRIDE   (B_IMG * BATCH_PER)   // 32768 elements per output tensor

#define NTH          1024                  // threads per block
#define HALF_CAP     1024                  // candidate capacity per group (fg | bg)
#define QPI          4                     // producer blocks (quarters) per image
#define QLEN         1025                  // K_TOT / QPI
#define CTR_BYTES    1024                  // arrival-counter region at front of ws

// Key packing (uint64 compare gives exact (fg, pri, idx) descending order;
// midx rides in the low bits — idx is unique so it never affects ordering):
//   bit 50      : fg flag
//   bits 49..20 : float bits of priority (pri in [0,1) => bits < 2^30;
//                 positive-float bits are order-isomorphic to values)
//   bits 19..7  : element index (0..4099 < 8192)  — reproduces the reversed-
//                 stable-argsort tiebreak (higher idx first on equal pri)
//   bits  6..0  : matched gt index (0..99 < 128)

// IoU with contraction disabled so float32 results match the numpy reference
// bit-for-bit (an FMA-induced 1-ulp drift at the 0.5 threshold would flip
// fg/bg and scramble integer outputs).
__device__ __forceinline__ float iou_fn(float ax1, float ay1, float ax2, float ay2,
                                        float area_a,
                                        float bx1, float by1, float bx2, float by2,
                                        float area_b) {
#pragma clang fp contract(off)
    float ltx = fmaxf(ax1, bx1), lty = fmaxf(ay1, by1);
    float rbx = fminf(ax2, bx2), rby = fminf(ay2, by2);
    float wx = fmaxf(rbx - ltx, 0.0f);
    float wy = fmaxf(rby - lty, 0.0f);
    float inter = wx * wy;
    float uni = area_a + area_b - inter;
    return inter > 0.0f ? inter / uni : 0.0f;
}

// ---------------------------------------------------------------------------
// Fused chip-wide kernel. Grid = B_IMG*QPI = 256 blocks x 1024 threads.
// Block blk: image b = blk>>2, quarter q = blk&3.
//   Phase A (all 256 blocks): IoU argmax + key build for its quarter -> ws.
//   Handoff: release-arrival on ctr[b]; owner (q==0) acquire-spins for 4.
//   Phase B (64 owner blocks): histogram-threshold top-k select + rank + emit.
// Deadlock-free without dispatch-order assumptions: 1024 thr + <=64 KiB LDS +
// __launch_bounds__(1024,8) (VGPR<=64) guarantee >=1 block/CU => all 256
// blocks co-resident on 256 CUs.
// ---------------------------------------------------------------------------
__global__ __launch_bounds__(NTH, 8) void fused_kernel(
        const float* __restrict__ gt_boxes,    // [B, M, 4]
        const float* __restrict__ prop_boxes,  // [B, N, 4]
        const int*   __restrict__ gt_classes,  // [B, M]
        const float* __restrict__ rand_pri,    // [B, K]
        uint64_t*    __restrict__ keys,        // [B, K] in ws (after ctr region)
        uint32_t*    __restrict__ ctr,         // [B] arrival counters (zeroed)
        float*       __restrict__ out)         // 5 x [B, 512] flat
{
    __shared__ uint64_t s_keys[K_TOT];         // 32.8 KB (owner phase B)
    __shared__ uint64_t s_cand[2 * HALF_CAP];  // 16 KB: fg half | bg half
    __shared__ int      s_hist[2][256];
    __shared__ float    s_gtb[M_GT * 4];
    __shared__ float    s_gta[M_GT];
    __shared__ int      s_gtc[M_GT];
    __shared__ float    s_out[5][BATCH_PER];   // 10 KB staging
    __shared__ int      s_T[2], s_needed[2], s_cnt[2];

    const int blk = blockIdx.x;
    const int b   = blk >> 2;
    const int q   = blk & 3;
    const int tid = threadIdx.x;

    // ---- stage gt data for image b ----
    for (int i = tid; i < M_GT * 4; i += NTH)
        s_gtb[i] = gt_boxes[(size_t)b * M_GT * 4 + i];
    for (int i = tid; i < M_GT; i += NTH)
        s_gtc[i] = gt_classes[(size_t)b * M_GT + i];
    __syncthreads();
    for (int m = tid; m < M_GT; m += NTH) {
#pragma clang fp contract(off)
        s_gta[m] = (s_gtb[m * 4 + 2] - s_gtb[m * 4 + 0]) *
                   (s_gtb[m * 4 + 3] - s_gtb[m * 4 + 1]);
    }
    __syncthreads();

    // ---- phase A: IoU argmax + key build for quarter q ----
    for (int t = tid; t < QLEN; t += NTH) {
        const int k = q * QLEN + t;            // 4*1025 == 4100: always < K_TOT
        float bx1, by1, bx2, by2;
        if (k < N_PROP) {
            const float4 p = *(const float4*)(prop_boxes + ((size_t)b * N_PROP + k) * 4);
            bx1 = p.x; by1 = p.y; bx2 = p.z; by2 = p.w;
        } else {
            const float* p = s_gtb + (k - N_PROP) * 4;
            bx1 = p[0]; by1 = p[1]; bx2 = p[2]; by2 = p[3];
        }
        float area_b;
        {
#pragma clang fp contract(off)
            area_b = (bx2 - bx1) * (by2 - by1);
        }
        float best = -1.0f; int bidx = 0;
#pragma unroll 4
        for (int m = 0; m < M_GT; ++m) {
            float iv = iou_fn(s_gtb[m*4+0], s_gtb[m*4+1], s_gtb[m*4+2], s_gtb[m*4+3],
                              s_gta[m], bx1, by1, bx2, by2, area_b);
            if (iv > best) { best = iv; bidx = m; }  // strict > => first-occurrence argmax
        }
        const bool fg = best >= 0.5f;
        const uint32_t pb = __float_as_uint(rand_pri[(size_t)b * K_TOT + k]);
        keys[(size_t)b * K_TOT + k] =
              (fg ? (1ull << 50) : 0ull)
            | ((uint64_t)pb << 20)
            | ((uint64_t)k  << 7)
            | (uint64_t)bidx;
    }
    __syncthreads();
    __threadfence();                            // make key stores device-visible
    if (tid == 0)
        __hip_atomic_fetch_add(&ctr[b], 1u, __ATOMIC_RELEASE, __HIP_MEMORY_SCOPE_AGENT);
    if (q != 0) return;                         // non-owner producers done

    // ---- owner: wait for all 4 producers of image b ----
    if (tid == 0) {
        while (__hip_atomic_load(&ctr[b], __ATOMIC_ACQUIRE, __HIP_MEMORY_SCOPE_AGENT) < (uint32_t)QPI)
            __builtin_amdgcn_s_sleep(2);
    }
    __syncthreads();

    // ---- phase B: load keys + histogram per group ----
    for (int i = tid; i < 512; i += NTH) s_hist[i >> 8][i & 255] = 0;
    if (tid < 2) s_cnt[tid] = 0;
    __syncthreads();
    for (int k = tid; k < K_TOT; k += NTH) {
        uint64_t key = keys[(size_t)b * K_TOT + k];
        s_keys[k] = key;
        int g = ((key >> 50) & 1ull) ? 0 : 1;   // 0 = fg, 1 = bg
        uint32_t pbits = (uint32_t)((key >> 20) & 0x3FFFFFFFull);
        int bucket = min(255, (int)(__uint_as_float(pbits) * 256.0f));  // monotone
        atomicAdd(&s_hist[g][bucket], 1);
    }
    __syncthreads();

    // Hillis-Steele suffix scan over each 256-bucket histogram
    for (int d = 1; d < 256; d <<= 1) {
        int v = 0, g = tid >> 8, t = tid & 255;
        bool act = (tid < 512) && (t + d < 256);
        if (act) v = s_hist[g][t + d];
        __syncthreads();
        if (act) s_hist[g][t] += v;
        __syncthreads();
    }

    if (tid == 0) {
        int fg_total = s_hist[0][0];
        int bg_total = s_hist[1][0];
        int nfg = min(NUM_FG_TGT, fg_total);
        int nbg = min(BATCH_PER - nfg, bg_total);
        s_needed[0] = nfg; s_needed[1] = nbg;
    }
    __syncthreads();

    // bucket threshold: max t with S[t] >= need (unique crossing; S non-increasing)
    if (tid < 512) {
        int g = tid >> 8, t = tid & 255;
        int need = s_needed[g];
        int St  = s_hist[g][t];
        int St1 = (t == 255) ? -1 : s_hist[g][t + 1];
        if (St >= need && St1 < need) s_T[g] = t;
    }
    if (tid < BATCH_PER) {                     // prefill invalid pattern
        s_out[0][tid] = 0.0f; s_out[1][tid] = -1.0f;
        s_out[2][tid] = -1.0f; s_out[3][tid] = -1.0f;
    }
    __syncthreads();

    const int nfg = s_needed[0], nbg = s_needed[1];
    if (tid < BATCH_PER)
        s_out[4][tid] = (tid < nfg + nbg) ? 1.0f : 0.0f;

    // compaction into disjoint halves (fg -> [0,HALF_CAP), bg -> [HALF_CAP,...))
    for (int k = tid; k < K_TOT; k += NTH) {
        uint64_t key = s_keys[k];
        int g = ((key >> 50) & 1ull) ? 0 : 1;
        uint32_t pbits = (uint32_t)((key >> 20) & 0x3FFFFFFFull);
        int bucket = min(255, (int)(__uint_as_float(pbits) * 256.0f));
        if (bucket >= s_T[g]) {
            int pos = atomicAdd(&s_cnt[g], 1);
            if (pos < HALF_CAP) s_cand[g * HALF_CAP + pos] = key;
        }
    }
    __syncthreads();

    // rank within each half (keys unique -> each slot written exactly once,
    // independent of atomic ordering) and emit
    const int fgc = min(s_cnt[0], HALF_CAP);
    const int bgc = min(s_cnt[1], HALF_CAP);
    for (int c = tid; c < fgc + bgc; c += NTH) {
        const bool isfg = (c < fgc);
        const int  base = isfg ? 0 : HALF_CAP;
        const int  cnt  = isfg ? fgc : bgc;
        const int  ci   = isfg ? c : (c - fgc);
        const uint64_t kc = s_cand[base + ci];
        int r = 0;
        for (int j = 0; j < cnt; ++j)          // broadcast LDS reads
            r += (s_cand[base + j] > kc) ? 1 : 0;
        int slot = -1;
        if (isfg) { if (r < nfg) slot = r; }
        else      { if (r < nbg) slot = nfg + r; }
        if (slot >= 0) {
            int idx = (int)((kc >> 7) & 0x1FFFull);
            int mi  = (int)(kc & 0x7Full);
            float bx1, by1, bx2, by2;
            if (idx < N_PROP) {
                const float4 p = *(const float4*)(prop_boxes + ((size_t)b * N_PROP + idx) * 4);
                bx1 = p.x; by1 = p.y; bx2 = p.z; by2 = p.w;
            } else {
                const float* p = s_gtb + (idx - N_PROP) * 4;
                bx1 = p[0]; by1 = p[1]; bx2 = p[2]; by2 = p[3];
            }
            float area_b;
            {
#pragma clang fp contract(off)
                area_b = (bx2 - bx1) * (by2 - by1);
            }
            // bit-exact matched_vals[idx]: same fp ops on same inputs as phase A
            float iou = iou_fn(s_gtb[mi*4+0], s_gtb[mi*4+1], s_gtb[mi*4+2], s_gtb[mi*4+3],
                               s_gta[mi], bx1, by1, bx2, by2, area_b);
            s_out[0][slot] = iou;
            s_out[1][slot] = (float)idx;
            s_out[2][slot] = (float)(isfg ? s_gtc[mi] : NUM_CLASSES_);
            s_out[3][slot] = (float)mi;
        }
    }
    __syncthreads();

    // coalesced write-out
    for (int i = tid; i < 5 * BATCH_PER; i += NTH) {
        int o = i / BATCH_PER, p = i % BATCH_PER;
        out[(size_t)o * OUT_STRIDE + (size_t)b * BATCH_PER + p] = s_out[o][p];
    }
}

// ---------------------------------------------------------------------------
// Fallback: R4's proven single kernel (one block per image, zero workspace).
// Used only if ws_size is too small for the key buffer + counters.
// ---------------------------------------------------------------------------
__global__ __launch_bounds__(NTH) void roiheads_fallback(
        const float* __restrict__ gt_boxes,
        const float* __restrict__ prop_boxes,
        const int*   __restrict__ gt_classes,
        const float* __restrict__ rand_pri,
        float*       __restrict__ out)
{
    __shared__ uint64_t s_keys[K_TOT];
    __shared__ uint64_t s_cand[2 * HALF_CAP];
    __shared__ int      s_hist[2][256];
    __shared__ float    s_gtb[M_GT * 4];
    __shared__ float    s_gta[M_GT];
    __shared__ int      s_gtc[M_GT];
    __shared__ float    s_out[5][BATCH_PER];
    __shared__ int      s_T[2], s_needed[2], s_cnt[2];

    const int b   = blockIdx.x;
    const int tid = threadIdx.x;

    for (int i = tid; i < 512; i += NTH) s_hist[i >> 8][i & 255] = 0;
    if (tid < 2) s_cnt[tid] = 0;
    for (int i = tid; i < M_GT * 4; i += NTH)
        s_gtb[i] = gt_boxes[(size_t)b * M_GT * 4 + i];
    for (int i = tid; i < M_GT; i += NTH)
        s_gtc[i] = gt_classes[(size_t)b * M_GT + i];
    __syncthreads();
    for (int m = tid; m < M_GT; m += NTH) {
#pragma clang fp contract(off)
        s_gta[m] = (s_gtb[m * 4 + 2] - s_gtb[m * 4 + 0]) *
                   (s_gtb[m * 4 + 3] - s_gtb[m * 4 + 1]);
    }
    __syncthreads();

    for (int k = tid; k < K_TOT; k += NTH) {
        float bx1, by1, bx2, by2;
        if (k < N_PROP) {
            const float4 p = *(const float4*)(prop_boxes + ((size_t)b * N_PROP + k) * 4);
            bx1 = p.x; by1 = p.y; bx2 = p.z; by2 = p.w;
        } else {
            const float* p = s_gtb + (k - N_PROP) * 4;
            bx1 = p[0]; by1 = p[1]; bx2 = p[2]; by2 = p[3];
        }
        float area_b;
        {
#pragma clang fp contract(off)
            area_b = (bx2 - bx1) * (by2 - by1);
        }
        float best = -1.0f; int bidx = 0;
        for (int m = 0; m < M_GT; ++m) {
            float iv = iou_fn(s_gtb[m*4+0], s_gtb[m*4+1], s_gtb[m*4+2], s_gtb[m*4+3],
                              s_gta[m], bx1, by1, bx2, by2, area_b);
            if (iv > best) { best = iv; bidx = m; }
        }
        const bool fg = best >= 0.5f;
        const float pri = rand_pri[(size_t)b * K_TOT + k];
        const uint32_t pb = __float_as_uint(pri);
        s_keys[k] = (fg ? (1ull << 50) : 0ull)
                  | ((uint64_t)pb << 20)
                  | ((uint64_t)k  << 7)
                  | (uint64_t)bidx;
        int g = fg ? 0 : 1;
        int bucket = min(255, (int)(pri * 256.0f));
        atomicAdd(&s_hist[g][bucket], 1);
    }
    __syncthreads();

    for (int d = 1; d < 256; d <<= 1) {
        int v = 0, g = tid >> 8, t = tid & 255;
        bool act = (tid < 512) && (t + d < 256);
        if (act) v = s_hist[g][t + d];
        __syncthreads();
        if (act) s_hist[g][t] += v;
        __syncthreads();
    }

    if (tid == 0) {
        int fg_total = s_hist[0][0];
        int bg_total = s_hist[1][0];
        int nfg = min(NUM_FG_TGT, fg_total);
        int nbg = min(BATCH_PER - nfg, bg_total);
        s_needed[0] = nfg; s_needed[1] = nbg;
    }
    __syncthreads();

    if (tid < 512) {
        int g = tid >> 8, t = tid & 255;
        int need = s_needed[g];
        int St  = s_hist[g][t];
        int St1 = (t == 255) ? -1 : s_hist[g][t + 1];
        if (St >= need && St1 < need) s_T[g] = t;
    }
    if (tid < BATCH_PER) {
        s_out[0][tid] = 0.0f; s_out[1][tid] = -1.0f;
        s_out[2][tid] = -1.0f; s_out[3][tid] = -1.0f;
    }
    __syncthreads();

    const int nfg = s_needed[0], nbg = s_needed[1];
    if (tid < BATCH_PER)
        s_out[4][tid] = (tid < nfg + nbg) ? 1.0f : 0.0f;

    for (int k = tid; k < K_TOT; k += NTH) {
        uint64_t key = s_keys[k];
        int g = ((key >> 50) & 1ull) ? 0 : 1;
        uint32_t pbits = (uint32_t)((key >> 20) & 0x3FFFFFFFull);
        int bucket = min(255, (int)(__uint_as_float(pbits) * 256.0f));
        if (bucket >= s_T[g]) {
            int pos = atomicAdd(&s_cnt[g], 1);
            if (pos < HALF_CAP) s_cand[g * HALF_CAP + pos] = key;
        }
    }
    __syncthreads();

    const int fgc = min(s_cnt[0], HALF_CAP);
    const int bgc = min(s_cnt[1], HALF_CAP);
    for (int c = tid; c < fgc + bgc; c += NTH) {
        const bool isfg = (c < fgc);
        const int  base = isfg ? 0 : HALF_CAP;
        const int  cnt  = isfg ? fgc : bgc;
        const int  ci   = isfg ? c : (c - fgc);
        const uint64_t kc = s_cand[base + ci];
        int r = 0;
        for (int j = 0; j < cnt; ++j)
            r += (s_cand[base + j] > kc) ? 1 : 0;
        int slot = -1;
        if (isfg) { if (r < nfg) slot = r; }
        else      { if (r < nbg) slot = nfg + r; }
        if (slot >= 0) {
            int idx = (int)((kc >> 7) & 0x1FFFull);
            int mi  = (int)(kc & 0x7Full);
            float bx1, by1, bx2, by2;
            if (idx < N_PROP) {
                const float4 p = *(const float4*)(prop_boxes + ((size_t)b * N_PROP + idx) * 4);
                bx1 = p.x; by1 = p.y; bx2 = p.z; by2 = p.w;
            } else {
                const float* p = s_gtb + (idx - N_PROP) * 4;
                bx1 = p[0]; by1 = p[1]; bx2 = p[2]; by2 = p[3];
            }
            float area_b;
            {
#pragma clang fp contract(off)
                area_b = (bx2 - bx1) * (by2 - by1);
            }
            float iou = iou_fn(s_gtb[mi*4+0], s_gtb[mi*4+1], s_gtb[mi*4+2], s_gtb[mi*4+3],
                               s_gta[mi], bx1, by1, bx2, by2, area_b);
            s_out[0][slot] = iou;
            s_out[1][slot] = (float)idx;
            s_out[2][slot] = (float)(isfg ? s_gtc[mi] : NUM_CLASSES_);
            s_out[3][slot] = (float)mi;
        }
    }
    __syncthreads();

    for (int i = tid; i < 5 * BATCH_PER; i += NTH) {
        int o = i / BATCH_PER, p = i % BATCH_PER;
        out[(size_t)o * OUT_STRIDE + (size_t)b * BATCH_PER + p] = s_out[o][p];
    }
}

extern "C" void kernel_launch(void* const* d_in, const int* in_sizes, int n_in,
                              void* d_out, int out_size, void* d_ws, size_t ws_size,
                              hipStream_t stream) {
    const float* gt_boxes   = (const float*)d_in[0];  // [64,100,4]
    const float* prop_boxes = (const float*)d_in[1];  // [64,4000,4]
    const int*   gt_classes = (const int*)  d_in[2];  // [64,100]
    const float* rand_pri   = (const float*)d_in[3];  // [64,4100]
    float* out = (float*)d_out;                       // 5 x [64,512] float32, concat

    const size_t need_ws = CTR_BYTES + (size_t)B_IMG * K_TOT * sizeof(uint64_t);
    if (d_ws != nullptr && ws_size >= need_ws) {
        uint32_t* ctr  = (uint32_t*)d_ws;
        uint64_t* keys = (uint64_t*)((char*)d_ws + CTR_BYTES);
        // zero arrival counters (captured into the graph, ordered on stream)
        hipMemsetAsync(d_ws, 0, CTR_BYTES, stream);
        fused_kernel<<<B_IMG * QPI, NTH, 0, stream>>>(gt_boxes, prop_boxes,
                                                      gt_classes, rand_pri,
                                                      keys, ctr, out);
    } else {
        roiheads_fallback<<<B_IMG, NTH, 0, stream>>>(gt_boxes, prop_boxes,
                                                     gt_classes, rand_pri, out);
    }
}